// Round 1
// baseline (360.714 us; speedup 1.0000x reference)
//
#include <hip/hip_runtime.h>
#include <stdint.h>

typedef __attribute__((ext_vector_type(8))) short short8;
typedef __attribute__((ext_vector_type(4))) float f32x4;

#define DEV static __device__ __forceinline__

DEV float b2f(unsigned short u) { union { float f; unsigned int i; } x; x.i = ((unsigned int)u) << 16; return x.f; }
DEV unsigned short f2b(float f) {
    union { float f; unsigned int i; } x; x.f = f;
    unsigned int r = x.i + 0x7fffu + ((x.i >> 16) & 1u);
    return (unsigned short)(r >> 16);
}
DEV void gld_lds16(const void* g, void* l) {
    __builtin_amdgcn_global_load_lds((const __attribute__((address_space(1))) void*)g,
                                     (__attribute__((address_space(3))) void*)l, 16, 0, 0);
}

__global__ void cast_f32_to_bf16(const float* __restrict__ in, unsigned short* __restrict__ out, long n8) {
    long i = (long)blockIdx.x * blockDim.x + threadIdx.x;
    long stride = (long)gridDim.x * blockDim.x;
    for (; i < n8; i += stride) {
        const f32x4* p = (const f32x4*)(in + i * 8);
        f32x4 a = p[0], b = p[1];
        short8 o;
        o[0] = (short)f2b(a[0]); o[1] = (short)f2b(a[1]); o[2] = (short)f2b(a[2]); o[3] = (short)f2b(a[3]);
        o[4] = (short)f2b(b[0]); o[5] = (short)f2b(b[1]); o[6] = (short)f2b(b[2]); o[7] = (short)f2b(b[3]);
        *(short8*)(out + i * 8) = o;
    }
}

__global__ __launch_bounds__(256) void gemm_nt(
    const unsigned short* __restrict__ A, int lda, long sAy, long sAz,
    const unsigned short* __restrict__ B, int ldb, long sBy, long sBz,
    float* __restrict__ C, int ldc, long sCy, long sCz,
    int M, int N, int K, int tn)
{
    A += (long)blockIdx.y * sAy + (long)blockIdx.z * sAz;
    B += (long)blockIdx.y * sBy + (long)blockIdx.z * sBz;
    C += (long)blockIdx.y * sCy + (long)blockIdx.z * sCz;
    int bid = blockIdx.x;
    int im = bid / tn, in_ = bid % tn;
    int m0 = im * 128, n0 = in_ * 128;
    __shared__ short As[128 * 64];
    __shared__ short Bs[128 * 64];
    int tid = threadIdx.x;
    int lane = tid & 63, wave = tid >> 6;
    int wu = __builtin_amdgcn_readfirstlane(wave);
    int wm = wave >> 1, wn = wave & 1;
    f32x4 acc[4][4];
#pragma unroll
    for (int m = 0; m < 4; m++)
#pragma unroll
        for (int n = 0; n < 4; n++) acc[m][n] = (f32x4){0.f, 0.f, 0.f, 0.f};

    for (int k0 = 0; k0 < K; k0 += 64) {
#pragma unroll
        for (int i = 0; i < 4; ++i) {
            int g = i * 256 + tid;
            int r = g >> 3, pc = g & 7;
            int cc = pc ^ (r & 7);
            const unsigned short* srcA = A + (long)(m0 + r) * lda + k0 + cc * 8;
            gld_lds16(srcA, As + (i * 256 + wu * 64) * 8);
            int rb = n0 + r; rb = rb < N ? rb : N - 1;
            const unsigned short* srcB = B + (long)rb * ldb + k0 + cc * 8;
            gld_lds16(srcB, Bs + (i * 256 + wu * 64) * 8);
        }
        __syncthreads();
#pragma unroll
        for (int ks = 0; ks < 2; ++ks) {
            short8 af[4], bfr[4];
#pragma unroll
            for (int m = 0; m < 4; ++m) {
                int r = wm * 64 + m * 16 + (lane & 15);
                int pc = (ks * 4 + (lane >> 4)) ^ (r & 7);
                af[m] = *(const short8*)(As + r * 64 + pc * 8);
            }
#pragma unroll
            for (int n = 0; n < 4; ++n) {
                int r = wn * 64 + n * 16 + (lane & 15);
                int pc = (ks * 4 + (lane >> 4)) ^ (r & 7);
                bfr[n] = *(const short8*)(Bs + r * 64 + pc * 8);
            }
#pragma unroll
            for (int m = 0; m < 4; ++m)
#pragma unroll
                for (int n = 0; n < 4; ++n)
                    acc[m][n] = __builtin_amdgcn_mfma_f32_16x16x32_bf16(af[m], bfr[n], acc[m][n], 0, 0, 0);
        }
        __syncthreads();
    }
    int rbase = m0 + wm * 64 + ((lane >> 4) << 2);
    int cbase = n0 + wn * 64 + (lane & 15);
#pragma unroll
    for (int m = 0; m < 4; ++m)
#pragma unroll
        for (int n = 0; n < 4; ++n) {
            int col = cbase + n * 16;
            if (col < N) {
#pragma unroll
                for (int r = 0; r < 4; ++r)
                    C[(long)(rbase + m * 16 + r) * ldc + col] = acc[m][n][r];
            }
        }
}

__global__ __launch_bounds__(256) void conv_dt_kernel(
    const float* __restrict__ proj,
    const float* __restrict__ conv_w, const float* __restrict__ conv_b,
    const float* __restrict__ dt_bias, const float* __restrict__ A_log,
    unsigned short* __restrict__ hs, unsigned short* __restrict__ Bb, unsigned short* __restrict__ Cb,
    float* __restrict__ dtv, float* __restrict__ dtA)
{
    int row = blockIdx.x;
    int b = row >> 11, t = row & 2047;
    int tid = threadIdx.x;
    __shared__ float sdt[32];
    if (tid < 32) {
        float v = proj[(long)row * 4384 + 4352 + tid] + dt_bias[tid];
        float dt = v > 20.f ? v : log1pf(__expf(v));
        sdt[tid] = dt;
        dtv[(long)(b * 32 + tid) * 2048 + t] = dt;
        dtA[(long)(b * 32 + tid) * 2048 + t] = -dt * __expf(A_log[tid]);
    }
    __syncthreads();
    for (int ch = tid; ch < 2304; ch += 256) {
        float acc = conv_b[ch];
#pragma unroll
        for (int k = 0; k < 4; ++k) {
            int tt = t - 3 + k;
            if (tt >= 0) acc += proj[(long)(b * 2048 + tt) * 4384 + 2048 + ch] * conv_w[ch * 4 + k];
        }
        float s = acc / (1.f + __expf(-acc));
        if (ch < 2048)      hs[(long)row * 2048 + ch] = f2b(s);
        else if (ch < 2176) Bb[(long)row * 128 + ch - 2048] = f2b(s);
        else                Cb[(long)row * 128 + ch - 2176] = f2b(s);
    }
}

__global__ __launch_bounds__(256) void cumsum_kernel(
    const float* __restrict__ dtA, float* __restrict__ Acum, float* __restrict__ Atot)
{
    int blk = blockIdx.x;
    int c = blk & 7, bh = blk >> 3;
    int l = threadIdx.x;
    __shared__ float s[256];
    float v = dtA[(long)bh * 2048 + c * 256 + l];
    s[l] = v;
    __syncthreads();
    for (int off = 1; off < 256; off <<= 1) {
        float x = (l >= off) ? s[l - off] : 0.f;
        __syncthreads();
        s[l] += x;
        __syncthreads();
    }
    Acum[(long)bh * 2048 + c * 256 + l] = s[l];
    if (l == 255) Atot[bh * 8 + c] = s[255];
}

__global__ __launch_bounds__(256) void transpose_kernel(
    const unsigned short* __restrict__ hs,
    const unsigned short* __restrict__ Bb,
    const float* __restrict__ dtv,
    const float* __restrict__ Acum,
    const float* __restrict__ Atot,
    unsigned short* __restrict__ xdtT,
    unsigned short* __restrict__ xdtd,
    unsigned short* __restrict__ BT)
{
    int b = blockIdx.y;
    int ct = blockIdx.x >> 5;
    int tt = blockIdx.x & 31;
    int c0 = ct * 64, t0 = tt * 64;
    __shared__ float tile[64][65];
    int tid = threadIdx.x;
    bool isB = (c0 >= 2048);
#pragma unroll
    for (int i = 0; i < 2; ++i) {
        int ci = i * 256 + tid;
        int r = ci >> 3, c8 = (ci & 7) * 8;
        const unsigned short* src;
        if (!isB) src = hs + ((long)(b * 2048 + t0 + r)) * 2048 + c0 + c8;
        else      src = Bb + ((long)(b * 2048 + t0 + r)) * 128 + (c0 - 2048) + c8;
        short8 v = *(const short8*)src;
#pragma unroll
        for (int j = 0; j < 8; ++j) tile[r][c8 + j] = b2f((unsigned short)v[j]);
    }
    __syncthreads();
#pragma unroll
    for (int i = 0; i < 2; ++i) {
        int co = i * 256 + tid;
        int oc = co >> 3, tc8 = (co & 7) * 8;
        int ch = c0 + oc;
        if (!isB) {
            int h = ch >> 6;
            long bh = b * 32 + h;
            short8 o1, o2;
#pragma unroll
            for (int j = 0; j < 8; ++j) {
                int t = t0 + tc8 + j;
                float v = tile[tc8 + j][oc];
                float dt = dtv[bh * 2048 + t];
                float dec = __expf(Atot[bh * 8 + (t >> 8)] - Acum[bh * 2048 + t]);
                float xv = v * dt;
                o1[j] = (short)f2b(xv);
                o2[j] = (short)f2b(xv * dec);
            }
            long off = ((long)(b * 2048 + ch)) * 2048 + t0 + tc8;
            *(short8*)(xdtT + off) = o1;
            *(short8*)(xdtd + off) = o2;
        } else {
            short8 o;
#pragma unroll
            for (int j = 0; j < 8; ++j) o[j] = (short)f2b(tile[tc8 + j][oc]);
            long off = ((long)(b * 128 + (ch - 2048))) * 2048 + t0 + tc8;
            *(short8*)(BT + off) = o;
        }
    }
}

__global__ __launch_bounds__(256) void ydiag_kernel(
    const unsigned short* __restrict__ Gm,
    const float* __restrict__ Acum,
    const unsigned short* __restrict__ xdtT,
    const unsigned short* __restrict__ hs,
    const float* __restrict__ Dp,
    float* __restrict__ y)
{
    int blk = blockIdx.x;
    int h = blk & 31, bc = blk >> 5;
    int c = bc & 7, b = bc >> 3;
    int tid = threadIdx.x, lane = tid & 63, wave = tid >> 6;
    __shared__ float sAc[256];
    __shared__ short Mb[256 * 64];
    sAc[tid] = Acum[(long)(b * 32 + h) * 2048 + c * 256 + tid];
    __syncthreads();
    f32x4 acc[4][4];
#pragma unroll
    for (int m = 0; m < 4; m++)
#pragma unroll
        for (int n = 0; n < 4; n++) acc[m][n] = (f32x4){0.f, 0.f, 0.f, 0.f};

    for (int zp = 0; zp < 4; ++zp) {
#pragma unroll
        for (int i = 0; i < 8; ++i) {
            int ci = i * 256 + tid;
            int s = ci >> 3, cz = ci & 7;
            int z0 = zp * 64 + cz * 8;
            short8 gv = *(const short8*)(Gm + ((long)bc * 256 + s) * 256 + z0);
            float as = sAc[s];
            short8 o;
#pragma unroll
            for (int j = 0; j < 8; ++j) {
                int z = z0 + j;
                float e = (s >= z) ? __expf(as - sAc[z]) : 0.f;
                o[j] = (short)f2b(b2f((unsigned short)gv[j]) * e);
            }
            *(short8*)(Mb + s * 64 + (cz ^ (s & 7)) * 8) = o;
        }
        __syncthreads();
#pragma unroll
        for (int ks = 0; ks < 2; ++ks) {
            short8 af[4], bfr[4];
#pragma unroll
            for (int m = 0; m < 4; ++m) {
                int r = wave * 64 + m * 16 + (lane & 15);
                int pc = (ks * 4 + (lane >> 4)) ^ (r & 7);
                af[m] = *(const short8*)(Mb + r * 64 + pc * 8);
            }
#pragma unroll
            for (int n = 0; n < 4; ++n) {
                int p = n * 16 + (lane & 15);
                int z = c * 256 + zp * 64 + ks * 32 + (lane >> 4) * 8;
                bfr[n] = *(const short8*)(xdtT + ((long)(b * 2048) + h * 64 + p) * 2048 + z);
            }
#pragma unroll
            for (int m = 0; m < 4; ++m)
#pragma unroll
                for (int n = 0; n < 4; ++n)
                    acc[m][n] = __builtin_amdgcn_mfma_f32_16x16x32_bf16(af[m], bfr[n], acc[m][n], 0, 0, 0);
        }
        __syncthreads();
    }
    float Dv = Dp[h];
#pragma unroll
    for (int m = 0; m < 4; ++m)
#pragma unroll
        for (int n = 0; n < 4; ++n) {
            int p = n * 16 + (lane & 15);
            int ch = h * 64 + p;
#pragma unroll
            for (int r = 0; r < 4; ++r) {
                int s = wave * 64 + m * 16 + ((lane >> 4) << 2) + r;
                long row_g = (long)b * 2048 + c * 256 + s;
                y[row_g * 2048 + ch] = acc[m][n][r] + b2f(hs[row_g * 2048 + ch]) * Dv;
            }
        }
}

__global__ __launch_bounds__(256) void scan_kernel(
    const float* __restrict__ states,
    const float* __restrict__ Atot,
    unsigned short* __restrict__ prevb)
{
    int bh = blockIdx.x;
    int b = bh >> 5, h = bh & 31;
    float ex[8];
#pragma unroll
    for (int c = 0; c < 8; ++c) ex[c] = __expf(Atot[bh * 8 + c]);
    for (int e = threadIdx.x; e < 8192; e += 256) {
        float S = 0.f;
#pragma unroll
        for (int c = 0; c < 8; ++c) {
            long idx = (long)((b * 8 + c) * 32 + h) * 8192 + e;
            prevb[idx] = f2b(S);
            S = ex[c] * S + states[idx];
        }
    }
}

__global__ __launch_bounds__(256) void yoff_kernel(
    const unsigned short* __restrict__ Cb,
    const unsigned short* __restrict__ prevb,
    const float* __restrict__ Acum,
    float* __restrict__ y)
{
    int blk = blockIdx.x;
    int h = blk & 31, bc = blk >> 5;
    int c = bc & 7, b = bc >> 3;
    int tid = threadIdx.x, lane = tid & 63, wave = tid >> 6;
    f32x4 acc[4][4];
#pragma unroll
    for (int m = 0; m < 4; m++)
#pragma unroll
        for (int n = 0; n < 4; n++) acc[m][n] = (f32x4){0.f, 0.f, 0.f, 0.f};
#pragma unroll
    for (int ks = 0; ks < 4; ++ks) {
        short8 af[4], bfr[4];
#pragma unroll
        for (int m = 0; m < 4; ++m) {
            int l = wave * 64 + m * 16 + (lane & 15);
            af[m] = *(const short8*)(Cb + ((long)b * 2048 + c * 256 + l) * 128 + ks * 32 + (lane >> 4) * 8);
        }
#pragma unroll
        for (int n = 0; n < 4; ++n) {
            int p = n * 16 + (lane & 15);
            bfr[n] = *(const short8*)(prevb + ((long)(bc * 32 + h) * 64 + p) * 128 + ks * 32 + (lane >> 4) * 8);
        }
#pragma unroll
        for (int m = 0; m < 4; ++m)
#pragma unroll
            for (int n = 0; n < 4; ++n)
                acc[m][n] = __builtin_amdgcn_mfma_f32_16x16x32_bf16(af[m], bfr[n], acc[m][n], 0, 0, 0);
    }
#pragma unroll
    for (int m = 0; m < 4; ++m)
#pragma unroll
        for (int r = 0; r < 4; ++r) {
            int l = wave * 64 + m * 16 + ((lane >> 4) << 2) + r;
            float sdec = __expf(Acum[(long)(b * 32 + h) * 2048 + c * 256 + l]);
            long row_g = (long)b * 2048 + c * 256 + l;
#pragma unroll
            for (int n = 0; n < 4; ++n) {
                int p = n * 16 + (lane & 15);
                y[row_g * 2048 + h * 64 + p] += acc[m][n][r] * sdec;
            }
        }
}

__global__ __launch_bounds__(256) void rmsnorm_kernel(
    const float* __restrict__ y, const float* __restrict__ proj,
    const float* __restrict__ norm_w, unsigned short* __restrict__ yn)
{
    int row = blockIdx.x;
    int tid = threadIdx.x, lane = tid & 63, wave = tid >> 6;
    int ch0 = tid * 8;
    const f32x4* yp = (const f32x4*)(y + (long)row * 2048 + ch0);
    const f32x4* gp = (const f32x4*)(proj + (long)row * 4384 + ch0);
    f32x4 yv0 = yp[0], yv1 = yp[1];
    f32x4 g0 = gp[0], g1 = gp[1];
    float v[8];
    float ss = 0.f;
#pragma unroll
    for (int j = 0; j < 4; ++j) {
        float g = g0[j]; float s = g / (1.f + __expf(-g));
        v[j] = yv0[j] * s; ss += v[j] * v[j];
        g = g1[j]; s = g / (1.f + __expf(-g));
        v[4 + j] = yv1[j] * s; ss += v[4 + j] * v[4 + j];
    }
#pragma unroll
    for (int off = 1; off < 64; off <<= 1) ss += __shfl_xor(ss, off);
    __shared__ float sw[4];
    if (lane == 0) sw[wave] = ss;
    __syncthreads();
    float tot = sw[0] + sw[1] + sw[2] + sw[3];
    float scale = rsqrtf(tot * (1.f / 2048.f) + 1e-6f);
    short8 o;
#pragma unroll
    for (int j = 0; j < 8; ++j) o[j] = (short)f2b(v[j] * scale * norm_w[ch0 + j]);
    *(short8*)(yn + (long)row * 2048 + ch0) = o;
}

extern "C" void kernel_launch(void* const* d_in, const int* in_sizes, int n_in,
                              void* d_out, int out_size, void* d_ws, size_t ws_size,
                              hipStream_t stream)
{
    const float* x        = (const float*)d_in[0];
    const float* in_proj  = (const float*)d_in[1];
    const float* conv_w   = (const float*)d_in[2];
    const float* conv_b   = (const float*)d_in[3];
    const float* dt_bias  = (const float*)d_in[4];
    const float* A_log    = (const float*)d_in[5];
    const float* Dp       = (const float*)d_in[6];
    const float* norm_w   = (const float*)d_in[7];
    const float* out_proj = (const float*)d_in[8];
    float* out = (float*)d_out;

    char* w = (char*)d_ws;
    auto alloc = [&](size_t bytes) { char* p = w; w += (bytes + 255) & ~(size_t)255; return p; };
    unsigned short* xb    = (unsigned short*)alloc(4096L * 1024 * 2);
    unsigned short* wb    = (unsigned short*)alloc(4384L * 1024 * 2);
    unsigned short* ob    = (unsigned short*)alloc(1024L * 2048 * 2);
    float*          proj  = (float*)        alloc(4096L * 4384 * 4);
    unsigned short* hs    = (unsigned short*)alloc(4096L * 2048 * 2);
    unsigned short* Bb    = (unsigned short*)alloc(4096L * 128 * 2);
    unsigned short* Cb    = (unsigned short*)alloc(4096L * 128 * 2);
    float*          dtv   = (float*)        alloc(64L * 2048 * 4);
    float*          dtA   = (float*)        alloc(64L * 2048 * 4);
    float*          Acum  = (float*)        alloc(64L * 2048 * 4);
    float*          Atot  = (float*)        alloc(64L * 8 * 4);
    unsigned short* xdtT  = (unsigned short*)alloc(2L * 2048 * 2048 * 2);
    unsigned short* xdtd  = (unsigned short*)alloc(2L * 2048 * 2048 * 2);
    unsigned short* BT    = (unsigned short*)alloc(2L * 128 * 2048 * 2);
    unsigned short* Gmb   = (unsigned short*)alloc(16L * 256 * 256 * 2);
    float*          Gmf   = (float*)        alloc(16L * 256 * 256 * 4);
    float*          yb    = (float*)        alloc(4096L * 2048 * 4);
    float*          states= (float*)        alloc(2L * 8 * 2048 * 128 * 4);
    unsigned short* prevb = (unsigned short*)alloc(2L * 8 * 2048 * 128 * 2);
    unsigned short* yn    = (unsigned short*)alloc(4096L * 2048 * 2);

    cast_f32_to_bf16<<<2048, 256, 0, stream>>>(x, xb, 4096L * 1024 / 8);
    cast_f32_to_bf16<<<2048, 256, 0, stream>>>(in_proj, wb, 4384L * 1024 / 8);
    cast_f32_to_bf16<<<1024, 256, 0, stream>>>(out_proj, ob, 1024L * 2048 / 8);

    gemm_nt<<<dim3(32 * 35, 1, 1), 256, 0, stream>>>(
        xb, 1024, 0, 0, wb, 1024, 0, 0, proj, 4384, 0, 0, 4096, 4384, 1024, 35);

    conv_dt_kernel<<<4096, 256, 0, stream>>>(proj, conv_w, conv_b, dt_bias, A_log,
                                             hs, Bb, Cb, dtv, dtA);

    cumsum_kernel<<<512, 256, 0, stream>>>(dtA, Acum, Atot);

    transpose_kernel<<<dim3(34 * 32, 2, 1), 256, 0, stream>>>(hs, Bb, dtv, Acum, Atot, xdtT, xdtd, BT);

    gemm_nt<<<dim3(4, 8, 2), 256, 0, stream>>>(
        Cb, 128, 256L * 128, 2048L * 128,
        Bb, 128, 256L * 128, 2048L * 128,
        Gmf, 256, 256L * 256, 8L * 256 * 256, 256, 256, 128, 2);
    cast_f32_to_bf16<<<512, 256, 0, stream>>>(Gmf, Gmb, 16L * 256 * 256 / 8);

    ydiag_kernel<<<512, 256, 0, stream>>>(Gmb, Acum, xdtT, hs, Dp, yb);

    gemm_nt<<<dim3(16, 8, 2), 256, 0, stream>>>(
        xdtd, 2048, 256, 2048L * 2048,
        BT, 2048, 256, 128L * 2048,
        states, 128, 2048L * 128, 8L * 2048 * 128, 2048, 128, 256, 1);

    scan_kernel<<<64, 256, 0, stream>>>(states, Atot, prevb);

    yoff_kernel<<<512, 256, 0, stream>>>(Cb, prevb, Acum, yb);

    rmsnorm_kernel<<<4096, 256, 0, stream>>>(yb, proj, norm_w, yn);

    gemm_nt<<<dim3(32 * 8, 1, 1), 256, 0, stream>>>(
        yn, 2048, 0, 0, ob, 2048, 0, 0, out, 1024, 0, 0, 4096, 1024, 2048, 8);
}

// Round 2
// 327.408 us; speedup vs baseline: 1.1017x; 1.1017x over previous
//
#include <hip/hip_runtime.h>
#include <stdint.h>

typedef __attribute__((ext_vector_type(8))) short short8;
typedef __attribute__((ext_vector_type(4))) float f32x4;

#define DEV static __device__ __forceinline__

DEV float b2f(unsigned short u) { union { float f; unsigned int i; } x; x.i = ((unsigned int)u) << 16; return x.f; }
DEV unsigned short f2b(float f) {
    union { float f; unsigned int i; } x; x.f = f;
    unsigned int r = x.i + 0x7fffu + ((x.i >> 16) & 1u);
    return (unsigned short)(r >> 16);
}
DEV void gld_lds16(const void* g, void* l) {
    __builtin_amdgcn_global_load_lds((const __attribute__((address_space(1))) void*)g,
                                     (__attribute__((address_space(3))) void*)l, 16, 0, 0);
}
DEV int xcd_swizzle(int bid, int nwg) {
    int q = nwg >> 3, r = nwg & 7;
    int xcd = bid & 7, base = bid >> 3;
    return (xcd < r ? xcd * (q + 1) : r * (q + 1) + (xcd - r) * q) + base;
}

__global__ void cast_f32_to_bf16(const float* __restrict__ in, unsigned short* __restrict__ out, long n8) {
    long i = (long)blockIdx.x * blockDim.x + threadIdx.x;
    long stride = (long)gridDim.x * blockDim.x;
    for (; i < n8; i += stride) {
        const f32x4* p = (const f32x4*)(in + i * 8);
        f32x4 a = p[0], b = p[1];
        short8 o;
        o[0] = (short)f2b(a[0]); o[1] = (short)f2b(a[1]); o[2] = (short)f2b(a[2]); o[3] = (short)f2b(a[3]);
        o[4] = (short)f2b(b[0]); o[5] = (short)f2b(b[1]); o[6] = (short)f2b(b[2]); o[7] = (short)f2b(b[3]);
        *(short8*)(out + i * 8) = o;
    }
}

// NT GEMM: C[m,n] = sum_k A[m,k]*B[n,k]. 128x128 tile, BK=64, 4 waves.
// OMODE 0: f32 C direct.  OMODE 1: bf16 C via LDS-transposed coalesced store.
// OMODE 2: bf16 C (cols<4352) + f32 dt split (cols 4352..4383) for in_proj.
template<int OMODE>
__global__ __launch_bounds__(256) void gemm_nt(
    const unsigned short* __restrict__ A, int lda, long sAy, long sAz,
    const unsigned short* __restrict__ B, int ldb, long sBy, long sBz,
    void* __restrict__ Cp, int ldc, long sCy, long sCz,
    float* __restrict__ dtout,
    int M, int N, int K, int tn)
{
    A += (long)blockIdx.y * sAy + (long)blockIdx.z * sAz;
    B += (long)blockIdx.y * sBy + (long)blockIdx.z * sBz;
    int bid = xcd_swizzle(blockIdx.x, gridDim.x);
    int im = bid / tn, in_ = bid % tn;
    int m0 = im * 128, n0 = in_ * 128;
    __shared__ short smem[2 * 128 * 64];
    short* As = smem;
    short* Bs = smem + 128 * 64;
    int tid = threadIdx.x;
    int lane = tid & 63, wave = tid >> 6;
    int wu = __builtin_amdgcn_readfirstlane(wave);
    int wm = wave >> 1, wn = wave & 1;
    f32x4 acc[4][4];
#pragma unroll
    for (int m = 0; m < 4; m++)
#pragma unroll
        for (int n = 0; n < 4; n++) acc[m][n] = (f32x4){0.f, 0.f, 0.f, 0.f};

    for (int k0 = 0; k0 < K; k0 += 64) {
#pragma unroll
        for (int i = 0; i < 4; ++i) {
            int g = i * 256 + tid;
            int r = g >> 3, pc = g & 7;
            int cc = pc ^ (r & 7);
            const unsigned short* srcA = A + (long)(m0 + r) * lda + k0 + cc * 8;
            gld_lds16(srcA, As + (i * 256 + wu * 64) * 8);
            int rb = n0 + r; rb = rb < N ? rb : N - 1;
            const unsigned short* srcB = B + (long)rb * ldb + k0 + cc * 8;
            gld_lds16(srcB, Bs + (i * 256 + wu * 64) * 8);
        }
        __syncthreads();
#pragma unroll
        for (int ks = 0; ks < 2; ++ks) {
            short8 af[4], bfr[4];
#pragma unroll
            for (int m = 0; m < 4; ++m) {
                int r = wm * 64 + m * 16 + (lane & 15);
                int pc = (ks * 4 + (lane >> 4)) ^ (r & 7);
                af[m] = *(const short8*)(As + r * 64 + pc * 8);
            }
#pragma unroll
            for (int n = 0; n < 4; ++n) {
                int r = wn * 64 + n * 16 + (lane & 15);
                int pc = (ks * 4 + (lane >> 4)) ^ (r & 7);
                bfr[n] = *(const short8*)(Bs + r * 64 + pc * 8);
            }
#pragma unroll
            for (int m = 0; m < 4; ++m)
#pragma unroll
                for (int n = 0; n < 4; ++n)
                    acc[m][n] = __builtin_amdgcn_mfma_f32_16x16x32_bf16(af[m], bfr[n], acc[m][n], 0, 0, 0);
        }
        __syncthreads();
    }
    int rbase = m0 + wm * 64 + ((lane >> 4) << 2);
    int cbase = n0 + wn * 64 + (lane & 15);
    if (OMODE == 0) {
        float* C = (float*)Cp;
        C += (long)blockIdx.y * sCy + (long)blockIdx.z * sCz;
#pragma unroll
        for (int m = 0; m < 4; ++m)
#pragma unroll
            for (int n = 0; n < 4; ++n) {
                int col = cbase + n * 16;
                if (col < N) {
#pragma unroll
                    for (int r = 0; r < 4; ++r)
                        C[(long)(rbase + m * 16 + r) * ldc + col] = acc[m][n][r];
                }
            }
    } else {
        if (OMODE == 2) {
            // dt columns written f32 directly from acc
#pragma unroll
            for (int m = 0; m < 4; ++m)
#pragma unroll
                for (int n = 0; n < 4; ++n) {
                    int col = cbase + n * 16;
                    if (col >= 4352 && col < N) {
#pragma unroll
                        for (int r = 0; r < 4; ++r)
                            dtout[(long)(rbase + m * 16 + r) * 32 + (col - 4352)] = acc[m][n][r];
                    }
                }
        }
        // bf16 path via LDS transpose (XOR swizzle for conflict-free writes)
        unsigned short* Cs = (unsigned short*)smem; // 128x128 bf16 = 32KB
        int rl = wm * 64 + ((lane >> 4) << 2);
        int cl = wn * 64 + (lane & 15);
#pragma unroll
        for (int m = 0; m < 4; ++m)
#pragma unroll
            for (int r = 0; r < 4; ++r) {
                int row = rl + m * 16 + r;
                int xr = ((row >> 2) & 3) << 4;
#pragma unroll
                for (int n = 0; n < 4; ++n)
                    Cs[row * 128 + ((cl + n * 16) ^ xr)] = f2b(acc[m][n][r]);
            }
        __syncthreads();
        unsigned short* C = (unsigned short*)Cp;
        C += (long)blockIdx.y * sCy + (long)blockIdx.z * sCz;
#pragma unroll
        for (int j = 0; j < 8; ++j) {
            int chunk = j * 256 + tid;
            int row = chunk >> 4, c8 = (chunk & 15) * 8;
            int col = n0 + c8;
            int xr = ((row >> 2) & 3) << 4;
            bool ok = (col < N) && !(OMODE == 2 && col >= 4352);
            if (ok)
                *(short8*)(C + (long)(m0 + row) * ldc + col) = *(const short8*)(Cs + row * 128 + (c8 ^ xr));
        }
    }
}

// conv1d (K=4 depthwise causal) + SiLU over bf16 proj; dt softplus from f32 dtraw
__global__ __launch_bounds__(256) void conv_dt_kernel(
    const unsigned short* __restrict__ projb,  // [4096,4384] bf16
    const float* __restrict__ dtraw,           // [4096,32]
    const float* __restrict__ conv_w, const float* __restrict__ conv_b,
    const float* __restrict__ dt_bias, const float* __restrict__ A_log,
    unsigned short* __restrict__ hs, unsigned short* __restrict__ Bb, unsigned short* __restrict__ Cb,
    float* __restrict__ dtv, float* __restrict__ dtA)
{
    int row = blockIdx.x;
    int b = row >> 11, t = row & 2047;
    int tid = threadIdx.x;
    if (tid < 32) {
        float v = dtraw[(long)row * 32 + tid] + dt_bias[tid];
        float dt = v > 20.f ? v : log1pf(__expf(v));
        dtv[(long)(b * 32 + tid) * 2048 + t] = dt;
        dtA[(long)(b * 32 + tid) * 2048 + t] = -dt * __expf(A_log[tid]);
    }
    // hs channels 0..2047, vectorized
    int ch0 = tid * 8;
    float a[8];
    {
        const f32x4* cb = (const f32x4*)(conv_b + ch0);
        f32x4 b0 = cb[0], b1 = cb[1];
#pragma unroll
        for (int j = 0; j < 4; ++j) { a[j] = b0[j]; a[4 + j] = b1[j]; }
    }
    f32x4 wv[8];
#pragma unroll
    for (int j = 0; j < 8; ++j) wv[j] = *(const f32x4*)(conv_w + (ch0 + j) * 4);
#pragma unroll
    for (int k = 0; k < 4; ++k) {
        int tt = t - 3 + k;
        if (tt >= 0) {
            short8 v = *(const short8*)(projb + (long)(b * 2048 + tt) * 4384 + 2048 + ch0);
#pragma unroll
            for (int j = 0; j < 8; ++j) a[j] += b2f((unsigned short)v[j]) * wv[j][k];
        }
    }
    short8 o;
#pragma unroll
    for (int j = 0; j < 8; ++j) { float s = a[j] / (1.f + __expf(-a[j])); o[j] = (short)f2b(s); }
    *(short8*)(hs + (long)row * 2048 + ch0) = o;
    // B/C channels 2048..2303 (one per thread)
    {
        int ch = 2048 + tid;
        float acc2 = conv_b[ch];
#pragma unroll
        for (int k = 0; k < 4; ++k) {
            int tt = t - 3 + k;
            if (tt >= 0) acc2 += b2f(projb[(long)(b * 2048 + tt) * 4384 + 2048 + ch]) * conv_w[ch * 4 + k];
        }
        float s = acc2 / (1.f + __expf(-acc2));
        if (tid < 128) Bb[(long)row * 128 + tid] = f2b(s);
        else           Cb[(long)row * 128 + tid - 128] = f2b(s);
    }
}

__global__ __launch_bounds__(256) void cumsum_kernel(
    const float* __restrict__ dtA, float* __restrict__ Acum, float* __restrict__ Atot)
{
    int blk = blockIdx.x;
    int c = blk & 7, bh = blk >> 3;
    int l = threadIdx.x;
    __shared__ float s[256];
    float v = dtA[(long)bh * 2048 + c * 256 + l];
    s[l] = v;
    __syncthreads();
    for (int off = 1; off < 256; off <<= 1) {
        float x = (l >= off) ? s[l - off] : 0.f;
        __syncthreads();
        s[l] += x;
        __syncthreads();
    }
    Acum[(long)bh * 2048 + c * 256 + l] = s[l];
    if (l == 255) Atot[bh * 8 + c] = s[255];
}

__global__ __launch_bounds__(256) void transpose_kernel(
    const unsigned short* __restrict__ hs,
    const unsigned short* __restrict__ Bb,
    const float* __restrict__ dtv,
    const float* __restrict__ Acum,
    const float* __restrict__ Atot,
    unsigned short* __restrict__ xdtT,
    unsigned short* __restrict__ xdtd,
    unsigned short* __restrict__ BT)
{
    int b = blockIdx.y;
    int ct = blockIdx.x >> 5;
    int tt = blockIdx.x & 31;
    int c0 = ct * 64, t0 = tt * 64;
    __shared__ float tile[64][65];
    int tid = threadIdx.x;
    bool isB = (c0 >= 2048);
#pragma unroll
    for (int i = 0; i < 2; ++i) {
        int ci = i * 256 + tid;
        int r = ci >> 3, c8 = (ci & 7) * 8;
        const unsigned short* src;
        if (!isB) src = hs + ((long)(b * 2048 + t0 + r)) * 2048 + c0 + c8;
        else      src = Bb + ((long)(b * 2048 + t0 + r)) * 128 + (c0 - 2048) + c8;
        short8 v = *(const short8*)src;
#pragma unroll
        for (int j = 0; j < 8; ++j) tile[r][c8 + j] = b2f((unsigned short)v[j]);
    }
    __syncthreads();
#pragma unroll
    for (int i = 0; i < 2; ++i) {
        int co = i * 256 + tid;
        int oc = co >> 3, tc8 = (co & 7) * 8;
        int ch = c0 + oc;
        if (!isB) {
            int h = ch >> 6;
            long bh = b * 32 + h;
            short8 o1, o2;
#pragma unroll
            for (int j = 0; j < 8; ++j) {
                int t = t0 + tc8 + j;
                float v = tile[tc8 + j][oc];
                float dt = dtv[bh * 2048 + t];
                float dec = __expf(Atot[bh * 8 + (t >> 8)] - Acum[bh * 2048 + t]);
                float xv = v * dt;
                o1[j] = (short)f2b(xv);
                o2[j] = (short)f2b(xv * dec);
            }
            long off = ((long)(b * 2048 + ch)) * 2048 + t0 + tc8;
            *(short8*)(xdtT + off) = o1;
            *(short8*)(xdtd + off) = o2;
        } else {
            short8 o;
#pragma unroll
            for (int j = 0; j < 8; ++j) o[j] = (short)f2b(tile[tc8 + j][oc]);
            long off = ((long)(b * 128 + (ch - 2048))) * 2048 + t0 + tc8;
            *(short8*)(BT + off) = o;
        }
    }
}

// Fused Y_diag + Y_off + D_res; writes y once.
__global__ __launch_bounds__(256) void ydiagoff_kernel(
    const unsigned short* __restrict__ Gm,    // [16,256,256] bf16
    const float* __restrict__ Acum,
    const unsigned short* __restrict__ xdtT,  // [b,2048,2048]
    const unsigned short* __restrict__ hs,
    const unsigned short* __restrict__ Cb,    // [b*L,128]
    const unsigned short* __restrict__ prevb, // [b,c,2048,128]
    const float* __restrict__ Dp,
    float* __restrict__ y)
{
    int blk = blockIdx.x;
    int h = blk & 31, bc = blk >> 5;
    int c = bc & 7, b = bc >> 3;
    int tid = threadIdx.x, lane = tid & 63, wave = tid >> 6;
    __shared__ float sAc[256];
    __shared__ short Mb[256 * 64];
    sAc[tid] = Acum[(long)(b * 32 + h) * 2048 + c * 256 + tid];
    __syncthreads();
    f32x4 acc[4][4];
#pragma unroll
    for (int m = 0; m < 4; m++)
#pragma unroll
        for (int n = 0; n < 4; n++) acc[m][n] = (f32x4){0.f, 0.f, 0.f, 0.f};

    for (int zp = 0; zp < 4; ++zp) {
#pragma unroll
        for (int i = 0; i < 8; ++i) {
            int ci = i * 256 + tid;
            int s = ci >> 3, cz = ci & 7;
            int z0 = zp * 64 + cz * 8;
            short8 gv = *(const short8*)(Gm + ((long)bc * 256 + s) * 256 + z0);
            float as = sAc[s];
            short8 o;
#pragma unroll
            for (int j = 0; j < 8; ++j) {
                int z = z0 + j;
                float e = (s >= z) ? __expf(as - sAc[z]) : 0.f;
                o[j] = (short)f2b(b2f((unsigned short)gv[j]) * e);
            }
            *(short8*)(Mb + s * 64 + (cz ^ (s & 7)) * 8) = o;
        }
        __syncthreads();
#pragma unroll
        for (int ks = 0; ks < 2; ++ks) {
            short8 af[4], bfr[4];
#pragma unroll
            for (int m = 0; m < 4; ++m) {
                int r = wave * 64 + m * 16 + (lane & 15);
                int pc = (ks * 4 + (lane >> 4)) ^ (r & 7);
                af[m] = *(const short8*)(Mb + r * 64 + pc * 8);
            }
#pragma unroll
            for (int n = 0; n < 4; ++n) {
                int p = n * 16 + (lane & 15);
                int z = c * 256 + zp * 64 + ks * 32 + (lane >> 4) * 8;
                bfr[n] = *(const short8*)(xdtT + ((long)(b * 2048) + h * 64 + p) * 2048 + z);
            }
#pragma unroll
            for (int m = 0; m < 4; ++m)
#pragma unroll
                for (int n = 0; n < 4; ++n)
                    acc[m][n] = __builtin_amdgcn_mfma_f32_16x16x32_bf16(af[m], bfr[n], acc[m][n], 0, 0, 0);
        }
        __syncthreads();
    }
    // Y_off: fold exp(Acum[l]) into C rows, accumulate into same acc
    float el[4];
#pragma unroll
    for (int m = 0; m < 4; ++m) el[m] = __expf(sAc[wave * 64 + m * 16 + (lane & 15)]);
#pragma unroll
    for (int ks = 0; ks < 4; ++ks) {
        short8 af[4], bfr[4];
#pragma unroll
        for (int m = 0; m < 4; ++m) {
            int l = wave * 64 + m * 16 + (lane & 15);
            short8 cv = *(const short8*)(Cb + ((long)b * 2048 + c * 256 + l) * 128 + ks * 32 + (lane >> 4) * 8);
#pragma unroll
            for (int j = 0; j < 8; ++j) af[m][j] = (short)f2b(b2f((unsigned short)cv[j]) * el[m]);
        }
#pragma unroll
        for (int n = 0; n < 4; ++n) {
            int p = n * 16 + (lane & 15);
            bfr[n] = *(const short8*)(prevb + ((long)(bc * 32 + h) * 64 + p) * 128 + ks * 32 + (lane >> 4) * 8);
        }
#pragma unroll
        for (int m = 0; m < 4; ++m)
#pragma unroll
            for (int n = 0; n < 4; ++n)
                acc[m][n] = __builtin_amdgcn_mfma_f32_16x16x32_bf16(af[m], bfr[n], acc[m][n], 0, 0, 0);
    }
    float Dv = Dp[h];
#pragma unroll
    for (int m = 0; m < 4; ++m)
#pragma unroll
        for (int n = 0; n < 4; ++n) {
            int p = n * 16 + (lane & 15);
            int ch = h * 64 + p;
#pragma unroll
            for (int r = 0; r < 4; ++r) {
                int s = wave * 64 + m * 16 + ((lane >> 4) << 2) + r;
                long row_g = (long)b * 2048 + c * 256 + s;
                y[row_g * 2048 + ch] = acc[m][n][r] + b2f(hs[row_g * 2048 + ch]) * Dv;
            }
        }
}

__global__ __launch_bounds__(256) void scan_kernel(
    const float* __restrict__ states,
    const float* __restrict__ Atot,
    unsigned short* __restrict__ prevb)
{
    int bh = blockIdx.x;
    int b = bh >> 5, h = bh & 31;
    float ex[8];
#pragma unroll
    for (int c = 0; c < 8; ++c) ex[c] = __expf(Atot[bh * 8 + c]);
    for (int e = threadIdx.x; e < 8192; e += 256) {
        float S = 0.f;
#pragma unroll
        for (int c = 0; c < 8; ++c) {
            long idx = (long)((b * 8 + c) * 32 + h) * 8192 + e;
            prevb[idx] = f2b(S);
            S = ex[c] * S + states[idx];
        }
    }
}

__global__ __launch_bounds__(256) void rmsnorm_kernel(
    const float* __restrict__ y, const unsigned short* __restrict__ projb,
    const float* __restrict__ norm_w, unsigned short* __restrict__ yn)
{
    int row = blockIdx.x;
    int tid = threadIdx.x, lane = tid & 63, wave = tid >> 6;
    int ch0 = tid * 8;
    const f32x4* yp = (const f32x4*)(y + (long)row * 2048 + ch0);
    f32x4 yv0 = yp[0], yv1 = yp[1];
    short8 g8 = *(const short8*)(projb + (long)row * 4384 + ch0);
    float v[8];
    float ss = 0.f;
#pragma unroll
    for (int j = 0; j < 8; ++j) {
        float g = b2f((unsigned short)g8[j]);
        float s = g / (1.f + __expf(-g));
        float yv = (j < 4) ? yv0[j] : yv1[j - 4];
        v[j] = yv * s; ss += v[j] * v[j];
    }
#pragma unroll
    for (int off = 1; off < 64; off <<= 1) ss += __shfl_xor(ss, off);
    __shared__ float sw[4];
    if (lane == 0) sw[wave] = ss;
    __syncthreads();
    float tot = sw[0] + sw[1] + sw[2] + sw[3];
    float scale = rsqrtf(tot * (1.f / 2048.f) + 1e-6f);
    short8 o;
#pragma unroll
    for (int j = 0; j < 8; ++j) o[j] = (short)f2b(v[j] * scale * norm_w[ch0 + j]);
    *(short8*)(yn + (long)row * 2048 + ch0) = o;
}

extern "C" void kernel_launch(void* const* d_in, const int* in_sizes, int n_in,
                              void* d_out, int out_size, void* d_ws, size_t ws_size,
                              hipStream_t stream)
{
    const float* x        = (const float*)d_in[0];
    const float* in_proj  = (const float*)d_in[1];
    const float* conv_w   = (const float*)d_in[2];
    const float* conv_b   = (const float*)d_in[3];
    const float* dt_bias  = (const float*)d_in[4];
    const float* A_log    = (const float*)d_in[5];
    const float* Dp       = (const float*)d_in[6];
    const float* norm_w   = (const float*)d_in[7];
    const float* out_proj = (const float*)d_in[8];
    float* out = (float*)d_out;

    char* w = (char*)d_ws;
    auto alloc = [&](size_t bytes) { char* p = w; w += (bytes + 255) & ~(size_t)255; return p; };
    unsigned short* xb    = (unsigned short*)alloc(4096L * 1024 * 2);
    unsigned short* wb    = (unsigned short*)alloc(4384L * 1024 * 2);
    unsigned short* ob    = (unsigned short*)alloc(1024L * 2048 * 2);
    unsigned short* projb = (unsigned short*)alloc(4096L * 4384 * 2);
    float*          dtraw = (float*)        alloc(4096L * 32 * 4);
    unsigned short* hs    = (unsigned short*)alloc(4096L * 2048 * 2);
    unsigned short* Bb    = (unsigned short*)alloc(4096L * 128 * 2);
    unsigned short* Cb    = (unsigned short*)alloc(4096L * 128 * 2);
    float*          dtv   = (float*)        alloc(64L * 2048 * 4);
    float*          dtA   = (float*)        alloc(64L * 2048 * 4);
    float*          Acum  = (float*)        alloc(64L * 2048 * 4);
    float*          Atot  = (float*)        alloc(64L * 8 * 4);
    unsigned short* xdtT  = (unsigned short*)alloc(2L * 2048 * 2048 * 2);
    unsigned short* xdtd  = (unsigned short*)alloc(2L * 2048 * 2048 * 2);
    unsigned short* BT    = (unsigned short*)alloc(2L * 128 * 2048 * 2);
    unsigned short* Gmb   = (unsigned short*)alloc(16L * 256 * 256 * 2);
    float*          yb    = (float*)        alloc(4096L * 2048 * 4);
    float*          states= (float*)        alloc(2L * 8 * 2048 * 128 * 4);
    unsigned short* prevb = (unsigned short*)alloc(2L * 8 * 2048 * 128 * 2);
    unsigned short* yn    = (unsigned short*)alloc(4096L * 2048 * 2);

    cast_f32_to_bf16<<<2048, 256, 0, stream>>>(x, xb, 4096L * 1024 / 8);
    cast_f32_to_bf16<<<2048, 256, 0, stream>>>(in_proj, wb, 4384L * 1024 / 8);
    cast_f32_to_bf16<<<1024, 256, 0, stream>>>(out_proj, ob, 1024L * 2048 / 8);

    // in_proj: projb[4096,4384] bf16 + dtraw f32
    gemm_nt<2><<<dim3(32 * 35, 1, 1), 256, 0, stream>>>(
        xb, 1024, 0, 0, wb, 1024, 0, 0, projb, 4384, 0, 0, dtraw, 4096, 4384, 1024, 35);

    conv_dt_kernel<<<4096, 256, 0, stream>>>(projb, dtraw, conv_w, conv_b, dt_bias, A_log,
                                             hs, Bb, Cb, dtv, dtA);

    cumsum_kernel<<<512, 256, 0, stream>>>(dtA, Acum, Atot);

    transpose_kernel<<<dim3(34 * 32, 2, 1), 256, 0, stream>>>(hs, Bb, dtv, Acum, Atot, xdtT, xdtd, BT);

    // Gm bf16 direct
    gemm_nt<1><<<dim3(4, 8, 2), 256, 0, stream>>>(
        Cb, 128, 256L * 128, 2048L * 128,
        Bb, 128, 256L * 128, 2048L * 128,
        Gmb, 256, 256L * 256, 8L * 256 * 256, nullptr, 256, 256, 128, 2);

    // states f32
    gemm_nt<0><<<dim3(16, 8, 2), 256, 0, stream>>>(
        xdtd, 2048, 256, 2048L * 2048,
        BT, 2048, 256, 128L * 2048,
        states, 128, 2048L * 128, 8L * 2048 * 128, nullptr, 2048, 128, 256, 1);

    scan_kernel<<<64, 256, 0, stream>>>(states, Atot, prevb);

    ydiagoff_kernel<<<512, 256, 0, stream>>>(Gmb, Acum, xdtT, hs, Cb, prevb, Dp, yb);

    rmsnorm_kernel<<<4096, 256, 0, stream>>>(yb, projb, norm_w, yn);

    gemm_nt<0><<<dim3(32 * 8, 1, 1), 256, 0, stream>>>(
        yn, 2048, 0, 0, ob, 2048, 0, 0, out, 1024, 0, 0, nullptr, 4096, 1024, 2048, 8);
}

// Round 3
// 299.098 us; speedup vs baseline: 1.2060x; 1.0947x over previous
//
#include <hip/hip_runtime.h>
#include <stdint.h>

typedef __attribute__((ext_vector_type(8))) short short8;
typedef __attribute__((ext_vector_type(4))) float f32x4;

#define DEV static __device__ __forceinline__

DEV float b2f(unsigned short u) { union { float f; unsigned int i; } x; x.i = ((unsigned int)u) << 16; return x.f; }
DEV unsigned short f2b(float f) {
    union { float f; unsigned int i; } x; x.f = f;
    unsigned int r = x.i + 0x7fffu + ((x.i >> 16) & 1u);
    return (unsigned short)(r >> 16);
}
DEV void gld_lds16(const void* g, void* l) {
    __builtin_amdgcn_global_load_lds((const __attribute__((address_space(1))) void*)g,
                                     (__attribute__((address_space(3))) void*)l, 16, 0, 0);
}
DEV int xcd_swizzle(int bid, int nwg) {
    int q = nwg >> 3, r = nwg & 7;
    int xcd = bid & 7, base = bid >> 3;
    return (xcd < r ? xcd * (q + 1) : r * (q + 1) + (xcd - r) * q) + base;
}

// one kernel for all three f32->bf16 casts
__global__ void cast3_kernel(const float* __restrict__ a, unsigned short* __restrict__ oa, long na8,
                             const float* __restrict__ b, unsigned short* __restrict__ ob_, long nb8,
                             const float* __restrict__ c, unsigned short* __restrict__ oc, long nc8) {
    long i = (long)blockIdx.x * blockDim.x + threadIdx.x;
    long stride = (long)gridDim.x * blockDim.x;
    long tot = na8 + nb8 + nc8;
    for (; i < tot; i += stride) {
        const float* src; unsigned short* dst; long j = i;
        if (j < na8) { src = a; dst = oa; }
        else if (j < na8 + nb8) { j -= na8; src = b; dst = ob_; }
        else { j -= na8 + nb8; src = c; dst = oc; }
        const f32x4* p = (const f32x4*)(src + j * 8);
        f32x4 v0 = p[0], v1 = p[1];
        short8 o;
        o[0] = (short)f2b(v0[0]); o[1] = (short)f2b(v0[1]); o[2] = (short)f2b(v0[2]); o[3] = (short)f2b(v0[3]);
        o[4] = (short)f2b(v1[0]); o[5] = (short)f2b(v1[1]); o[6] = (short)f2b(v1[2]); o[7] = (short)f2b(v1[3]);
        *(short8*)(dst + j * 8) = o;
    }
}

// NT GEMM: C[m,n] = sum_k A[m,k]*B[n,k]. 128x128 tile, BK=64, 4 waves.
// Double-buffered LDS + counted vmcnt pipeline (T3/T4-minimum): stages for tile
// t+1 stay in flight across the barrier; vmcnt only drains to 0 on last tile.
// OMODE 0: f32 C.  OMODE 1: bf16 C via LDS transpose.  OMODE 2: bf16 C + f32 dt cols.
template<int OMODE>
__global__ __launch_bounds__(256) void gemm_nt(
    const unsigned short* __restrict__ A, int lda, long sAy, long sAz,
    const unsigned short* __restrict__ B, int ldb, long sBy, long sBz,
    void* __restrict__ Cp, int ldc, long sCy, long sCz,
    float* __restrict__ dtout,
    int M, int N, int K, int tn)
{
    A += (long)blockIdx.y * sAy + (long)blockIdx.z * sAz;
    B += (long)blockIdx.y * sBy + (long)blockIdx.z * sBz;
    int bid = xcd_swizzle(blockIdx.x, gridDim.x);
    int im = bid / tn, in_ = bid % tn;
    int m0 = im * 128, n0 = in_ * 128;
    __shared__ short smem[2 * 2 * 128 * 64];   // 2 slots x (As 8192 + Bs 8192) shorts = 64 KB
    int tid = threadIdx.x;
    int lane = tid & 63, wave = tid >> 6;
    int wu = __builtin_amdgcn_readfirstlane(wave);
    int wm = wave >> 1, wn = wave & 1;
    f32x4 acc[4][4];
#pragma unroll
    for (int m = 0; m < 4; m++)
#pragma unroll
        for (int n = 0; n < 4; n++) acc[m][n] = (f32x4){0.f, 0.f, 0.f, 0.f};

    auto stage = [&](int k0, int s) {
        short* As = smem + s * 16384;
        short* Bs = As + 8192;
#pragma unroll
        for (int i = 0; i < 4; ++i) {
            int g = i * 256 + tid;
            int r = g >> 3, pc = g & 7;
            int cc = pc ^ (r & 7);
            gld_lds16(A + (long)(m0 + r) * lda + k0 + cc * 8, As + (i * 256 + wu * 64) * 8);
            int rb = n0 + r; rb = rb < N ? rb : N - 1;
            gld_lds16(B + (long)rb * ldb + k0 + cc * 8, Bs + (i * 256 + wu * 64) * 8);
        }
    };

    int nt = K >> 6;
    stage(0, 0);                                   // prologue: tile 0 -> slot 0
    for (int t = 0; t < nt; ++t) {
        int cur = t & 1;
        if (t + 1 < nt) {
            stage((t + 1) << 6, cur ^ 1);          // issue next tile's 8 loads first
            asm volatile("s_waitcnt vmcnt(8)" ::: "memory");   // tile t landed; t+1 in flight
        } else {
            asm volatile("s_waitcnt vmcnt(0)" ::: "memory");   // last tile: full drain
        }
        __builtin_amdgcn_s_barrier();
        const short* As = smem + cur * 16384;
        const short* Bs = As + 8192;
#pragma unroll
        for (int ks = 0; ks < 2; ++ks) {
            short8 af[4], bfr[4];
#pragma unroll
            for (int m = 0; m < 4; ++m) {
                int r = wm * 64 + m * 16 + (lane & 15);
                int pc = (ks * 4 + (lane >> 4)) ^ (r & 7);
                af[m] = *(const short8*)(As + r * 64 + pc * 8);
            }
#pragma unroll
            for (int n = 0; n < 4; ++n) {
                int r = wn * 64 + n * 16 + (lane & 15);
                int pc = (ks * 4 + (lane >> 4)) ^ (r & 7);
                bfr[n] = *(const short8*)(Bs + r * 64 + pc * 8);
            }
            __builtin_amdgcn_s_setprio(1);
#pragma unroll
            for (int m = 0; m < 4; ++m)
#pragma unroll
                for (int n = 0; n < 4; ++n)
                    acc[m][n] = __builtin_amdgcn_mfma_f32_16x16x32_bf16(af[m], bfr[n], acc[m][n], 0, 0, 0);
            __builtin_amdgcn_s_setprio(0);
        }
        __builtin_amdgcn_s_barrier();              // slot cur free for next iter's stage
    }

    int rbase = m0 + wm * 64 + ((lane >> 4) << 2);
    int cbase = n0 + wn * 64 + (lane & 15);
    if (OMODE == 0) {
        float* C = (float*)Cp;
        C += (long)blockIdx.y * sCy + (long)blockIdx.z * sCz;
#pragma unroll
        for (int m = 0; m < 4; ++m)
#pragma unroll
            for (int n = 0; n < 4; ++n) {
                int col = cbase + n * 16;
                if (col < N) {
#pragma unroll
                    for (int r = 0; r < 4; ++r)
                        C[(long)(rbase + m * 16 + r) * ldc + col] = acc[m][n][r];
                }
            }
    } else {
        if (OMODE == 2) {
#pragma unroll
            for (int m = 0; m < 4; ++m)
#pragma unroll
                for (int n = 0; n < 4; ++n) {
                    int col = cbase + n * 16;
                    if (col >= 4352 && col < N) {
#pragma unroll
                        for (int r = 0; r < 4; ++r)
                            dtout[(long)(rbase + m * 16 + r) * 32 + (col - 4352)] = acc[m][n][r];
                    }
                }
        }
        unsigned short* Cs = (unsigned short*)smem; // 32 KB of the 64 KB
        int rl = wm * 64 + ((lane >> 4) << 2);
        int cl = wn * 64 + (lane & 15);
#pragma unroll
        for (int m = 0; m < 4; ++m)
#pragma unroll
            for (int r = 0; r < 4; ++r) {
                int row = rl + m * 16 + r;
                int xr = ((row >> 2) & 3) << 4;
#pragma unroll
                for (int n = 0; n < 4; ++n)
                    Cs[row * 128 + ((cl + n * 16) ^ xr)] = f2b(acc[m][n][r]);
            }
        __syncthreads();
        unsigned short* C = (unsigned short*)Cp;
        C += (long)blockIdx.y * sCy + (long)blockIdx.z * sCz;
#pragma unroll
        for (int j = 0; j < 8; ++j) {
            int chunk = j * 256 + tid;
            int row = chunk >> 4, c8 = (chunk & 15) * 8;
            int col = n0 + c8;
            int xr = ((row >> 2) & 3) << 4;
            bool ok = (col < N) && !(OMODE == 2 && col >= 4352);
            if (ok)
                *(short8*)(C + (long)(m0 + row) * ldc + col) = *(const short8*)(Cs + row * 128 + (c8 ^ xr));
        }
    }
}

__global__ __launch_bounds__(256) void conv_dt_kernel(
    const unsigned short* __restrict__ projb,
    const float* __restrict__ dtraw,
    const float* __restrict__ conv_w, const float* __restrict__ conv_b,
    const float* __restrict__ dt_bias, const float* __restrict__ A_log,
    unsigned short* __restrict__ hs, unsigned short* __restrict__ Bb, unsigned short* __restrict__ Cb,
    float* __restrict__ dtv, float* __restrict__ dtA)
{
    int row = blockIdx.x;
    int b = row >> 11, t = row & 2047;
    int tid = threadIdx.x;
    if (tid < 32) {
        float v = dtraw[(long)row * 32 + tid] + dt_bias[tid];
        float dt = v > 20.f ? v : log1pf(__expf(v));
        dtv[(long)(b * 32 + tid) * 2048 + t] = dt;
        dtA[(long)(b * 32 + tid) * 2048 + t] = -dt * __expf(A_log[tid]);
    }
    int ch0 = tid * 8;
    float a[8];
    {
        const f32x4* cb = (const f32x4*)(conv_b + ch0);
        f32x4 b0 = cb[0], b1 = cb[1];
#pragma unroll
        for (int j = 0; j < 4; ++j) { a[j] = b0[j]; a[4 + j] = b1[j]; }
    }
    f32x4 wv[8];
#pragma unroll
    for (int j = 0; j < 8; ++j) wv[j] = *(const f32x4*)(conv_w + (ch0 + j) * 4);
#pragma unroll
    for (int k = 0; k < 4; ++k) {
        int tt = t - 3 + k;
        if (tt >= 0) {
            short8 v = *(const short8*)(projb + (long)(b * 2048 + tt) * 4384 + 2048 + ch0);
#pragma unroll
            for (int j = 0; j < 8; ++j) a[j] += b2f((unsigned short)v[j]) * wv[j][k];
        }
    }
    short8 o;
#pragma unroll
    for (int j = 0; j < 8; ++j) { float s = a[j] / (1.f + __expf(-a[j])); o[j] = (short)f2b(s); }
    *(short8*)(hs + (long)row * 2048 + ch0) = o;
    {
        int ch = 2048 + tid;
        float acc2 = conv_b[ch];
#pragma unroll
        for (int k = 0; k < 4; ++k) {
            int tt = t - 3 + k;
            if (tt >= 0) acc2 += b2f(projb[(long)(b * 2048 + tt) * 4384 + 2048 + ch]) * conv_w[ch * 4 + k];
        }
        float s = acc2 / (1.f + __expf(-acc2));
        if (tid < 128) Bb[(long)row * 128 + tid] = f2b(s);
        else           Cb[(long)row * 128 + tid - 128] = f2b(s);
    }
}

__global__ __launch_bounds__(256) void cumsum_kernel(
    const float* __restrict__ dtA, float* __restrict__ Acum, float* __restrict__ Atot)
{
    int blk = blockIdx.x;
    int c = blk & 7, bh = blk >> 3;
    int l = threadIdx.x;
    __shared__ float s[256];
    float v = dtA[(long)bh * 2048 + c * 256 + l];
    s[l] = v;
    __syncthreads();
    for (int off = 1; off < 256; off <<= 1) {
        float x = (l >= off) ? s[l - off] : 0.f;
        __syncthreads();
        s[l] += x;
        __syncthreads();
    }
    Acum[(long)bh * 2048 + c * 256 + l] = s[l];
    if (l == 255) Atot[bh * 8 + c] = s[255];
}

__global__ __launch_bounds__(256) void transpose_kernel(
    const unsigned short* __restrict__ hs,
    const unsigned short* __restrict__ Bb,
    const float* __restrict__ dtv,
    const float* __restrict__ Acum,
    const float* __restrict__ Atot,
    unsigned short* __restrict__ xdtT,
    unsigned short* __restrict__ xdtd,
    unsigned short* __restrict__ BT)
{
    int b = blockIdx.y;
    int ct = blockIdx.x >> 5;
    int tt = blockIdx.x & 31;
    int c0 = ct * 64, t0 = tt * 64;
    __shared__ float tile[64][65];
    int tid = threadIdx.x;
    bool isB = (c0 >= 2048);
#pragma unroll
    for (int i = 0; i < 2; ++i) {
        int ci = i * 256 + tid;
        int r = ci >> 3, c8 = (ci & 7) * 8;
        const unsigned short* src;
        if (!isB) src = hs + ((long)(b * 2048 + t0 + r)) * 2048 + c0 + c8;
        else      src = Bb + ((long)(b * 2048 + t0 + r)) * 128 + (c0 - 2048) + c8;
        short8 v = *(const short8*)src;
#pragma unroll
        for (int j = 0; j < 8; ++j) tile[r][c8 + j] = b2f((unsigned short)v[j]);
    }
    __syncthreads();
#pragma unroll
    for (int i = 0; i < 2; ++i) {
        int co = i * 256 + tid;
        int oc = co >> 3, tc8 = (co & 7) * 8;
        int ch = c0 + oc;
        if (!isB) {
            int h = ch >> 6;
            long bh = b * 32 + h;
            short8 o1, o2;
#pragma unroll
            for (int j = 0; j < 8; ++j) {
                int t = t0 + tc8 + j;
                float v = tile[tc8 + j][oc];
                float dt = dtv[bh * 2048 + t];
                float dec = __expf(Atot[bh * 8 + (t >> 8)] - Acum[bh * 2048 + t]);
                float xv = v * dt;
                o1[j] = (short)f2b(xv);
                o2[j] = (short)f2b(xv * dec);
            }
            long off = ((long)(b * 2048 + ch)) * 2048 + t0 + tc8;
            *(short8*)(xdtT + off) = o1;
            *(short8*)(xdtd + off) = o2;
        } else {
            short8 o;
#pragma unroll
            for (int j = 0; j < 8; ++j) o[j] = (short)f2b(tile[tc8 + j][oc]);
            long off = ((long)(b * 128 + (ch - 2048))) * 2048 + t0 + tc8;
            *(short8*)(BT + off) = o;
        }
    }
}

__global__ __launch_bounds__(256) void ydiagoff_kernel(
    const unsigned short* __restrict__ Gm,
    const float* __restrict__ Acum,
    const unsigned short* __restrict__ xdtT,
    const unsigned short* __restrict__ hs,
    const unsigned short* __restrict__ Cb,
    const unsigned short* __restrict__ prevb,
    const float* __restrict__ Dp,
    float* __restrict__ y)
{
    int blk = blockIdx.x;
    int h = blk & 31, bc = blk >> 5;
    int c = bc & 7, b = bc >> 3;
    int tid = threadIdx.x, lane = tid & 63, wave = tid >> 6;
    __shared__ float sAc[256];
    __shared__ short Mb[256 * 64];
    sAc[tid] = Acum[(long)(b * 32 + h) * 2048 + c * 256 + tid];
    __syncthreads();
    f32x4 acc[4][4];
#pragma unroll
    for (int m = 0; m < 4; m++)
#pragma unroll
        for (int n = 0; n < 4; n++) acc[m][n] = (f32x4){0.f, 0.f, 0.f, 0.f};

    for (int zp = 0; zp < 4; ++zp) {
#pragma unroll
        for (int i = 0; i < 8; ++i) {
            int ci = i * 256 + tid;
            int s = ci >> 3, cz = ci & 7;
            int z0 = zp * 64 + cz * 8;
            short8 gv = *(const short8*)(Gm + ((long)bc * 256 + s) * 256 + z0);
            float as = sAc[s];
            short8 o;
#pragma unroll
            for (int j = 0; j < 8; ++j) {
                int z = z0 + j;
                float e = (s >= z) ? __expf(as - sAc[z]) : 0.f;
                o[j] = (short)f2b(b2f((unsigned short)gv[j]) * e);
            }
            *(short8*)(Mb + s * 64 + (cz ^ (s & 7)) * 8) = o;
        }
        __syncthreads();
#pragma unroll
        for (int ks = 0; ks < 2; ++ks) {
            short8 af[4], bfr[4];
#pragma unroll
            for (int m = 0; m < 4; ++m) {
                int r = wave * 64 + m * 16 + (lane & 15);
                int pc = (ks * 4 + (lane >> 4)) ^ (r & 7);
                af[m] = *(const short8*)(Mb + r * 64 + pc * 8);
            }
#pragma unroll
            for (int n = 0; n < 4; ++n) {
                int p = n * 16 + (lane & 15);
                int z = c * 256 + zp * 64 + ks * 32 + (lane >> 4) * 8;
                bfr[n] = *(const short8*)(xdtT + ((long)(b * 2048) + h * 64 + p) * 2048 + z);
            }
#pragma unroll
            for (int m = 0; m < 4; ++m)
#pragma unroll
                for (int n = 0; n < 4; ++n)
                    acc[m][n] = __builtin_amdgcn_mfma_f32_16x16x32_bf16(af[m], bfr[n], acc[m][n], 0, 0, 0);
        }
        __syncthreads();
    }
    float el[4];
#pragma unroll
    for (int m = 0; m < 4; ++m) el[m] = __expf(sAc[wave * 64 + m * 16 + (lane & 15)]);
#pragma unroll
    for (int ks = 0; ks < 4; ++ks) {
        short8 af[4], bfr[4];
#pragma unroll
        for (int m = 0; m < 4; ++m) {
            int l = wave * 64 + m * 16 + (lane & 15);
            short8 cv = *(const short8*)(Cb + ((long)b * 2048 + c * 256 + l) * 128 + ks * 32 + (lane >> 4) * 8);
#pragma unroll
            for (int j = 0; j < 8; ++j) af[m][j] = (short)f2b(b2f((unsigned short)cv[j]) * el[m]);
        }
#pragma unroll
        for (int n = 0; n < 4; ++n) {
            int p = n * 16 + (lane & 15);
            bfr[n] = *(const short8*)(prevb + ((long)(bc * 32 + h) * 64 + p) * 128 + ks * 32 + (lane >> 4) * 8);
        }
#pragma unroll
        for (int m = 0; m < 4; ++m)
#pragma unroll
            for (int n = 0; n < 4; ++n)
                acc[m][n] = __builtin_amdgcn_mfma_f32_16x16x32_bf16(af[m], bfr[n], acc[m][n], 0, 0, 0);
    }
    float Dv = Dp[h];
#pragma unroll
    for (int m = 0; m < 4; ++m)
#pragma unroll
        for (int n = 0; n < 4; ++n) {
            int p = n * 16 + (lane & 15);
            int ch = h * 64 + p;
#pragma unroll
            for (int r = 0; r < 4; ++r) {
                int s = wave * 64 + m * 16 + ((lane >> 4) << 2) + r;
                long row_g = (long)b * 2048 + c * 256 + s;
                y[row_g * 2048 + ch] = acc[m][n][r] + b2f(hs[row_g * 2048 + ch]) * Dv;
            }
        }
}

__global__ __launch_bounds__(256) void scan_kernel(
    const float* __restrict__ states,
    const float* __restrict__ Atot,
    unsigned short* __restrict__ prevb)
{
    int bh = blockIdx.x;
    int b = bh >> 5, h = bh & 31;
    float ex[8];
#pragma unroll
    for (int c = 0; c < 8; ++c) ex[c] = __expf(Atot[bh * 8 + c]);
    for (int e = threadIdx.x; e < 8192; e += 256) {
        float S = 0.f;
#pragma unroll
        for (int c = 0; c < 8; ++c) {
            long idx = (long)((b * 8 + c) * 32 + h) * 8192 + e;
            prevb[idx] = f2b(S);
            S = ex[c] * S + states[idx];
        }
    }
}

__global__ __launch_bounds__(256) void rmsnorm_kernel(
    const float* __restrict__ y, const unsigned short* __restrict__ projb,
    const float* __restrict__ norm_w, unsigned short* __restrict__ yn)
{
    int row = blockIdx.x;
    int tid = threadIdx.x, lane = tid & 63, wave = tid >> 6;
    int ch0 = tid * 8;
    const f32x4* yp = (const f32x4*)(y + (long)row * 2048 + ch0);
    f32x4 yv0 = yp[0], yv1 = yp[1];
    short8 g8 = *(const short8*)(projb + (long)row * 4384 + ch0);
    float v[8];
    float ss = 0.f;
#pragma unroll
    for (int j = 0; j < 8; ++j) {
        float g = b2f((unsigned short)g8[j]);
        float s = g / (1.f + __expf(-g));
        float yv = (j < 4) ? yv0[j] : yv1[j - 4];
        v[j] = yv * s; ss += v[j] * v[j];
    }
#pragma unroll
    for (int off = 1; off < 64; off <<= 1) ss += __shfl_xor(ss, off);
    __shared__ float sw[4];
    if (lane == 0) sw[wave] = ss;
    __syncthreads();
    float tot = sw[0] + sw[1] + sw[2] + sw[3];
    float scale = rsqrtf(tot * (1.f / 2048.f) + 1e-6f);
    short8 o;
#pragma unroll
    for (int j = 0; j < 8; ++j) o[j] = (short)f2b(v[j] * scale * norm_w[ch0 + j]);
    *(short8*)(yn + (long)row * 2048 + ch0) = o;
}

extern "C" void kernel_launch(void* const* d_in, const int* in_sizes, int n_in,
                              void* d_out, int out_size, void* d_ws, size_t ws_size,
                              hipStream_t stream)
{
    const float* x        = (const float*)d_in[0];
    const float* in_proj  = (const float*)d_in[1];
    const float* conv_w   = (const float*)d_in[2];
    const float* conv_b   = (const float*)d_in[3];
    const float* dt_bias  = (const float*)d_in[4];
    const float* A_log    = (const float*)d_in[5];
    const float* Dp       = (const float*)d_in[6];
    const float* norm_w   = (const float*)d_in[7];
    const float* out_proj = (const float*)d_in[8];
    float* out = (float*)d_out;

    char* w = (char*)d_ws;
    auto alloc = [&](size_t bytes) { char* p = w; w += (bytes + 255) & ~(size_t)255; return p; };
    unsigned short* xb    = (unsigned short*)alloc(4096L * 1024 * 2);
    unsigned short* wb    = (unsigned short*)alloc(4384L * 1024 * 2);
    unsigned short* ob    = (unsigned short*)alloc(1024L * 2048 * 2);
    unsigned short* projb = (unsigned short*)alloc(4096L * 4384 * 2);
    float*          dtraw = (float*)        alloc(4096L * 32 * 4);
    unsigned short* hs    = (unsigned short*)alloc(4096L * 2048 * 2);
    unsigned short* Bb    = (unsigned short*)alloc(4096L * 128 * 2);
    unsigned short* Cb    = (unsigned short*)alloc(4096L * 128 * 2);
    float*          dtv   = (float*)        alloc(64L * 2048 * 4);
    float*          dtA   = (float*)        alloc(64L * 2048 * 4);
    float*          Acum  = (float*)        alloc(64L * 2048 * 4);
    float*          Atot  = (float*)        alloc(64L * 8 * 4);
    unsigned short* xdtT  = (unsigned short*)alloc(2L * 2048 * 2048 * 2);
    unsigned short* xdtd  = (unsigned short*)alloc(2L * 2048 * 2048 * 2);
    unsigned short* BT    = (unsigned short*)alloc(2L * 128 * 2048 * 2);
    unsigned short* Gmb   = (unsigned short*)alloc(16L * 256 * 256 * 2);
    float*          yb    = (float*)        alloc(4096L * 2048 * 4);
    float*          states= (float*)        alloc(2L * 8 * 2048 * 128 * 4);
    unsigned short* prevb = (unsigned short*)alloc(2L * 8 * 2048 * 128 * 2);
    unsigned short* yn    = (unsigned short*)alloc(4096L * 2048 * 2);

    cast3_kernel<<<2048, 256, 0, stream>>>(x, xb, 4096L * 1024 / 8,
                                           in_proj, wb, 4384L * 1024 / 8,
                                           out_proj, ob, 1024L * 2048 / 8);

    gemm_nt<2><<<dim3(32 * 35, 1, 1), 256, 0, stream>>>(
        xb, 1024, 0, 0, wb, 1024, 0, 0, projb, 4384, 0, 0, dtraw, 4096, 4384, 1024, 35);

    conv_dt_kernel<<<4096, 256, 0, stream>>>(projb, dtraw, conv_w, conv_b, dt_bias, A_log,
                                             hs, Bb, Cb, dtv, dtA);

    cumsum_kernel<<<512, 256, 0, stream>>>(dtA, Acum, Atot);

    transpose_kernel<<<dim3(34 * 32, 2, 1), 256, 0, stream>>>(hs, Bb, dtv, Acum, Atot, xdtT, xdtd, BT);

    gemm_nt<1><<<dim3(4, 8, 2), 256, 0, stream>>>(
        Cb, 128, 256L * 128, 2048L * 128,
        Bb, 128, 256L * 128, 2048L * 128,
        Gmb, 256, 256L * 256, 8L * 256 * 256, nullptr, 256, 256, 128, 2);

    gemm_nt<0><<<dim3(16, 8, 2), 256, 0, stream>>>(
        xdtd, 2048, 256, 2048L * 2048,
        BT, 2048, 256, 128L * 2048,
        states, 128, 2048L * 128, 8L * 2048 * 128, nullptr, 2048, 128, 256, 1);

    scan_kernel<<<64, 256, 0, stream>>>(states, Atot, prevb);

    ydiagoff_kernel<<<512, 256, 0, stream>>>(Gmb, Acum, xdtT, hs, Cb, prevb, Dp, yb);

    rmsnorm_kernel<<<4096, 256, 0, stream>>>(yb, projb, norm_w, yn);

    gemm_nt<0><<<dim3(32 * 8, 1, 1), 256, 0, stream>>>(
        yn, 2048, 0, 0, ob, 2048, 0, 0, out, 1024, 0, 0, nullptr, 4096, 1024, 2048, 8);
}